// Round 2
// 1019.380 us; speedup vs baseline: 1.1674x; 1.1674x over previous
//
#include <hip/hip_runtime.h>

typedef _Float16 half8_t __attribute__((ext_vector_type(8)));
typedef _Float16 half2_t __attribute__((ext_vector_type(2)));
typedef float floatx4 __attribute__((ext_vector_type(4)));

#define B_DIM 256
#define T_DIM 512
#define E_DIM 256
#define H_DIM 256
#define MROWS (B_DIM * T_DIM)  // 131072 rows of [B*T, E]

__device__ __forceinline__ half2_t mk2(_Float16 x, _Float16 y) {
    half2_t v; v[0] = x; v[1] = y; return v;
}

// ---------------------------------------------------------------------------
// Phase 1: X[m][n] = emb[m][:E] . Wg[n][:E] + bg[n]  for gates g in {z,r,m}
//   gate 0 -> Xz (f16, ws), gate 1 -> Xr (f16, ws), gate 2 -> Xm (f32, d_out)
// f16 MFMA 16x16x32, 128x128 tiles, BK=32, fp32->f16 convert fused in staging.
// (unchanged — verified correct at 1190 µs total)
// ---------------------------------------------------------------------------
__global__ __launch_bounds__(256, 2) void gemm_x(
    const float* __restrict__ emb,
    const float* __restrict__ Wz, const float* __restrict__ bz,
    const float* __restrict__ Wr, const float* __restrict__ br,
    const float* __restrict__ Wm, const float* __restrict__ bm,
    _Float16* __restrict__ Xz, _Float16* __restrict__ Xr,
    float* __restrict__ Xm)
{
    const int n0 = blockIdx.x * 128;        // 0..640 (6 n-tiles over 3 gates)
    const int m0 = blockIdx.y * 128;
    const int gate = n0 >> 8;               // 128-tile pairs per gate
    const int ng0 = n0 & 255;
    const float* W    = (gate == 0) ? Wz : (gate == 1) ? Wr : Wm;
    const float* bias = (gate == 0) ? bz : (gate == 1) ? br : bm;

    // padded row stride 40 halves (80 B): 16B-aligned rows, <=2-way bank alias
    __shared__ __align__(16) _Float16 lA[128 * 40];
    __shared__ __align__(16) _Float16 lB[128 * 40];

    const int t = threadIdx.x;
    const int lane = t & 63;
    const int wave = t >> 6;
    const int wm = (wave >> 1) * 64;
    const int wn = (wave & 1) * 64;
    const int lq = lane >> 4;               // quad
    const int lr = lane & 15;

    floatx4 acc[4][4];
    #pragma unroll
    for (int i = 0; i < 4; ++i)
        #pragma unroll
        for (int j = 0; j < 4; ++j)
            acc[i][j] = (floatx4)0.0f;

    const int srow = t >> 1;                // 0..127
    const int scol = (t & 1) * 16;          // 0 or 16 (halves within 32-k tile)
    const float* aSrc = emb + (size_t)(m0 + srow) * E_DIM + scol;
    const float* bSrc = W + (size_t)(ng0 + srow) * (E_DIM + H_DIM) + scol;

    for (int k0 = 0; k0 < E_DIM; k0 += 32) {
        float ta[16], tb[16];
        #pragma unroll
        for (int u = 0; u < 4; ++u) {
            *(float4*)(ta + 4 * u) = *(const float4*)(aSrc + k0 + 4 * u);
            *(float4*)(tb + 4 * u) = *(const float4*)(bSrc + k0 + 4 * u);
        }
        half8_t a0, a1, b0, b1;
        #pragma unroll
        for (int u = 0; u < 8; ++u) {
            a0[u] = (_Float16)ta[u]; a1[u] = (_Float16)ta[u + 8];
            b0[u] = (_Float16)tb[u]; b1[u] = (_Float16)tb[u + 8];
        }
        __syncthreads();   // previous iter's LDS reads done
        *(half8_t*)&lA[srow * 40 + scol]     = a0;
        *(half8_t*)&lA[srow * 40 + scol + 8] = a1;
        *(half8_t*)&lB[srow * 40 + scol]     = b0;
        *(half8_t*)&lB[srow * 40 + scol + 8] = b1;
        __syncthreads();

        half8_t af[4], bf[4];
        #pragma unroll
        for (int i = 0; i < 4; ++i)
            af[i] = *(const half8_t*)&lA[(wm + i * 16 + lr) * 40 + lq * 8];
        #pragma unroll
        for (int j = 0; j < 4; ++j)
            bf[j] = *(const half8_t*)&lB[(wn + j * 16 + lr) * 40 + lq * 8];
        #pragma unroll
        for (int i = 0; i < 4; ++i)
            #pragma unroll
            for (int j = 0; j < 4; ++j)
                acc[i][j] = __builtin_amdgcn_mfma_f32_16x16x32_f16(
                    af[i], bf[j], acc[i][j], 0, 0, 0);
    }

    // epilogue: D[row=(lane>>4)*4+r][col=lane&15], add bias, store per gate
    if (gate < 2) {
        _Float16* dst = (gate == 0) ? Xz : Xr;
        #pragma unroll
        for (int j = 0; j < 4; ++j) {
            const int ng = ng0 + wn + j * 16 + lr;
            const float bv = bias[ng];
            #pragma unroll
            for (int i = 0; i < 4; ++i) {
                const int mrow = m0 + wm + i * 16 + lq * 4;
                #pragma unroll
                for (int r = 0; r < 4; ++r)
                    dst[(size_t)(mrow + r) * H_DIM + ng] =
                        (_Float16)(acc[i][j][r] + bv);
            }
        }
    } else {
        #pragma unroll
        for (int j = 0; j < 4; ++j) {
            const int ng = ng0 + wn + j * 16 + lr;
            const float bv = bias[ng];
            #pragma unroll
            for (int i = 0; i < 4; ++i) {
                const int mrow = m0 + wm + i * 16 + lq * 4;
                #pragma unroll
                for (int r = 0; r < 4; ++r)
                    Xm[(size_t)(mrow + r) * H_DIM + ng] = acc[i][j][r] + bv;
            }
        }
    }
}

// ---------------------------------------------------------------------------
// Phase 2: persistent recurrence, MFMA matvec version.
// One WG (512 thr = 8 waves) per batch element, 256 WGs on 256 CUs.
//
// Trick: mfma_f32_16x16x32_f16 with the B-fragment loaded IDENTICALLY in
// every lane (B[col][k] independent of col=lane&15) computes the same matvec
// W.h in all 16 D-columns -> every lane holds 4 valid outputs
// (rows lq*4+{0..3} of its m-tile), no cross-lane fixup needed.
//
// Recurrent weights live in VGPRs in A-fragment layout (A[row=lr][k=lq*8+j]):
//   waves 0-3: z-gate, m-tiles (w&3)*4+i (i=0..3)   -> af[4][8], 128 VGPRs
//   waves 4-7: r-gate, same m-tile split            -> (same af)
//   all waves: m-gate, m-tiles w*2+i (i=0..1)       -> am[2][8],  64 VGPRs
//
// Per step: phase A (z,r matvecs + sigmoid; z->zl, r*h->rh) | barrier |
//           phase B (m matvec on rh + tanh + h update)      | barrier.
// Epilogues redistribute so each lane handles exactly one output row via a
// static cndmask tree (no runtime-indexed vector arrays -> no scratch).
// ---------------------------------------------------------------------------
__device__ __forceinline__ float pick4(floatx4 v, int r) {
    float x01 = (r & 1) ? v[1] : v[0];
    float x23 = (r & 1) ? v[3] : v[2];
    return (r & 2) ? x23 : x01;
}

__global__ __launch_bounds__(512, 2) void gru_rec(
    const float* __restrict__ Wz,
    const float* __restrict__ Wr,
    const float* __restrict__ Wm,
    const _Float16* __restrict__ Xz,
    const _Float16* __restrict__ Xr,
    float* __restrict__ out)   // holds Xm on entry per row; overwritten with h
{
    const int b = blockIdx.x;
    const int t = threadIdx.x;
    const int w    = t >> 6;        // wave 0..7
    const int lane = t & 63;
    const int lr   = lane & 15;     // D column / A row-in-tile
    const int lq   = lane >> 4;     // D row-quad / A k-octet

    __shared__ __align__(16) _Float16 hh[256];  // h as f16 (MFMA B operand)
    __shared__ __align__(16) float    hf[256];  // h master fp32
    __shared__ __align__(16) _Float16 rh[256];  // r*h as f16
    __shared__ __align__(16) float    zl[256];  // z gate values

    // ---- load recurrent-weight A fragments into registers (fp32 -> f16) ----
    half8_t af[4][8];   // phase A: gate w>>2, m-tiles (w&3)*4 + i
    {
        const float* Wg = (w < 4) ? Wz : Wr;
        #pragma unroll
        for (int i = 0; i < 4; ++i) {
            const float* rp = Wg +
                (size_t)(((w & 3) * 4 + i) * 16 + lr) * (E_DIM + H_DIM) +
                E_DIM + lq * 8;
            #pragma unroll
            for (int kt = 0; kt < 8; ++kt) {
                float4 f0 = *(const float4*)(rp + kt * 32);
                float4 f1 = *(const float4*)(rp + kt * 32 + 4);
                half8_t hv;
                hv[0] = (_Float16)f0.x; hv[1] = (_Float16)f0.y;
                hv[2] = (_Float16)f0.z; hv[3] = (_Float16)f0.w;
                hv[4] = (_Float16)f1.x; hv[5] = (_Float16)f1.y;
                hv[6] = (_Float16)f1.z; hv[7] = (_Float16)f1.w;
                af[i][kt] = hv;
            }
        }
    }
    half8_t am[2][8];   // phase B: m gate, m-tiles w*2 + i
    {
        #pragma unroll
        for (int i = 0; i < 2; ++i) {
            const float* rp = Wm +
                (size_t)((w * 2 + i) * 16 + lr) * (E_DIM + H_DIM) +
                E_DIM + lq * 8;
            #pragma unroll
            for (int kt = 0; kt < 8; ++kt) {
                float4 f0 = *(const float4*)(rp + kt * 32);
                float4 f1 = *(const float4*)(rp + kt * 32 + 4);
                half8_t hv;
                hv[0] = (_Float16)f0.x; hv[1] = (_Float16)f0.y;
                hv[2] = (_Float16)f0.z; hv[3] = (_Float16)f0.w;
                hv[4] = (_Float16)f1.x; hv[5] = (_Float16)f1.y;
                hv[6] = (_Float16)f1.z; hv[7] = (_Float16)f1.w;
                am[i][kt] = hv;
            }
        }
    }

    if (t < 256) { hh[t] = (_Float16)0.0f; hf[t] = 0.0f; }
    __syncthreads();

    // per-lane output-row ownership (one row per lane)
    //   phase A: i = lr>>2, r = lr&3 -> row in [ (w&3)*64 , +64 )
    const int rowA = (w & 3) * 64 + (lr >> 2) * 16 + lq * 4 + (lr & 3);
    //   phase B: i = (lr>>2)&1, r = lr&3, active lanes lr<8 -> row in [w*32,+32)
    const int row2 = w * 32 + ((lr >> 2) & 1) * 16 + lq * 4 + (lr & 3);

    const size_t rowbase = (size_t)b * T_DIM * H_DIM;
    const _Float16* Xg = (w < 4) ? Xz : Xr;

    // step-0 prefetch
    _Float16 xg_p = Xg[rowbase + rowA];
    float    xm_p = (lr < 8) ? out[rowbase + row2] : 0.0f;

    for (int ts = 0; ts < T_DIM; ++ts) {
        // ---- phase A: (Wz_h.h | Wr_h.h) via MFMA, then sigmoid ----
        floatx4 acc[4];
        acc[0] = (floatx4)0.0f; acc[1] = (floatx4)0.0f;
        acc[2] = (floatx4)0.0f; acc[3] = (floatx4)0.0f;
        #pragma unroll
        for (int kt = 0; kt < 8; ++kt) {
            half8_t bf = *(const half8_t*)&hh[kt * 32 + lq * 8]; // bcast/lq
            #pragma unroll
            for (int i = 0; i < 4; ++i)
                acc[i] = __builtin_amdgcn_mfma_f32_16x16x32_f16(
                    af[i][kt], bf, acc[i], 0, 0, 0);
        }
        {
            const int r = lr & 3;
            float s0 = pick4(acc[0], r), s1 = pick4(acc[1], r);
            float s2 = pick4(acc[2], r), s3 = pick4(acc[3], r);
            float v = (lr & 8) ? ((lr & 4) ? s3 : s2)
                               : ((lr & 4) ? s1 : s0);
            const float a = v + (float)xg_p;
            const float g = 1.0f / (1.0f + __expf(-a));
            if (w < 4) zl[rowA] = g;                        // z
            else       rh[rowA] = (_Float16)(g * hf[rowA]); // r*h
        }
        if (ts + 1 < T_DIM)     // prefetch next step's X contribution
            xg_p = Xg[rowbase + (size_t)(ts + 1) * H_DIM + rowA];
        __syncthreads();

        // ---- phase B: Wm_h.(r*h) via MFMA, then tanh + h update ----
        floatx4 acc2[2];
        acc2[0] = (floatx4)0.0f; acc2[1] = (floatx4)0.0f;
        #pragma unroll
        for (int kt = 0; kt < 8; ++kt) {
            half8_t bfm = *(const half8_t*)&rh[kt * 32 + lq * 8];
            #pragma unroll
            for (int i = 0; i < 2; ++i)
                acc2[i] = __builtin_amdgcn_mfma_f32_16x16x32_f16(
                    am[i][kt], bfm, acc2[i], 0, 0, 0);
        }
        if (lr < 8) {
            const int r = lr & 3;
            float u0 = pick4(acc2[0], r), u1 = pick4(acc2[1], r);
            float v2 = (lr & 4) ? u1 : u0;
            const float amv = v2 + xm_p;                    // + Xm + bm
            const float hc  = 2.0f / (1.0f + __expf(-2.0f * amv)) - 1.0f;
            const float z   = zl[row2];
            const float hp  = hf[row2];
            const float hn  = hp + z * (hc - hp);
            out[rowbase + (size_t)ts * H_DIM + row2] = hn;
            hf[row2] = hn;
            hh[row2] = (_Float16)hn;
            if (ts + 1 < T_DIM)
                xm_p = out[rowbase + (size_t)(ts + 1) * H_DIM + row2];
        }
        __syncthreads();
    }
}

extern "C" void kernel_launch(void* const* d_in, const int* in_sizes, int n_in,
                              void* d_out, int out_size, void* d_ws, size_t ws_size,
                              hipStream_t stream) {
    (void)in_sizes; (void)n_in; (void)out_size; (void)ws_size;
    const float* emb = (const float*)d_in[0];
    const float* Wz  = (const float*)d_in[1];
    const float* bz  = (const float*)d_in[2];
    const float* Wr  = (const float*)d_in[3];
    const float* br  = (const float*)d_in[4];
    const float* Wm  = (const float*)d_in[5];
    const float* bm  = (const float*)d_in[6];
    float* out = (float*)d_out;

    _Float16* Xz = (_Float16*)d_ws;                      // [131072][256] f16
    _Float16* Xr = Xz + (size_t)MROWS * H_DIM;           // [131072][256] f16

    dim3 g1(6, MROWS / 128);
    gemm_x<<<g1, 256, 0, stream>>>(emb, Wz, bz, Wr, br, Wm, bm, Xz, Xr, out);
    gru_rec<<<B_DIM, 512, 0, stream>>>(Wz, Wr, Wm, Xz, Xr, out);
}